// Round 3
// baseline (311.940 us; speedup 1.0000x reference)
//
#include <hip/hip_runtime.h>
#include <hip/hip_bf16.h>
#include <math.h>

typedef __bf16 bf16t;
typedef __bf16 bf8v __attribute__((ext_vector_type(8)));
typedef float  f4v  __attribute__((ext_vector_type(4)));

#define DD  4
#define FF  64
#define HH  128
#define FIN 129

// XOR-swizzled LDS index within a 32-row x 128-col bf16 slab:
// 16B chunk (k>>3) XORed with (row&7) -> conflict-free ds_read_b128 at pitch 128.
__device__ __forceinline__ int swz(int row, int k) {
  return row * HH + ((((k >> 3) ^ (row & 7)) << 3) | (k & 7));
}

// ---- weight prep: f32 -> bf16 transpose to [n][k], LDS-tiled, coalesced both sides ----
// one block per 128x128 matrix: 0-3 w1[d], 4-7 w2[d], 8 w3
__global__ void prep_weights(const float* __restrict__ w1,
                             const float* __restrict__ w2,
                             const float* __restrict__ w3,
                             bf16t* __restrict__ w1t,
                             bf16t* __restrict__ w2t,
                             bf16t* __restrict__ w3t,
                             float* __restrict__ w1last) {
  __shared__ bf16t tile[128 * 65];  // [n][k-half] padded
  const int m = blockIdx.x;
  const float* src;
  bf16t* dst;
  if (m < 4)      { src = w1 + m * FIN * HH;       dst = w1t + m * HH * HH; }
  else if (m < 8) { src = w2 + (m - 4) * HH * HH;  dst = w2t + (m - 4) * HH * HH; }
  else            { src = w3;                       dst = w3t; }
  const int tid = threadIdx.x;
  for (int h = 0; h < 2; ++h) {
    __syncthreads();
    // read 64 k-rows x 128 n-cols, coalesced in n; store transposed into LDS
    for (int i = 0; i < 32; ++i) {
      int idx = tid + i * 256;
      int k = idx >> 7, n = idx & 127;
      tile[n * 65 + k] = (bf16t)src[(h * 64 + k) * HH + n];
    }
    __syncthreads();
    // write [n][k], coalesced in k
    for (int i = 0; i < 32; ++i) {
      int idx = tid + i * 256;
      int n = idx >> 6, k = idx & 63;
      dst[n * HH + h * 64 + k] = tile[n * 65 + k];
    }
  }
  if (m < 4 && tid < HH) w1last[m * HH + tid] = src[128 * HH + tid];
}

// ---- fully fused, barrier-free: 1 wave per block, 32 rows per wave ----
__launch_bounds__(64, 2)
__global__ void fourier_mlp(
    const float* __restrict__ cont,   // [N,4]
    const float* __restrict__ freqs,  // [4,64]
    const float* __restrict__ b1,     // [4,128]
    const float* __restrict__ ln1g,
    const float* __restrict__ ln1b,
    const float* __restrict__ b2,
    const float* __restrict__ outg,   // [128]
    const float* __restrict__ outb,
    const float* __restrict__ b3,
    const bf16t* __restrict__ w1t,    // [4][128][128] bf16, [d][n][k]
    const bf16t* __restrict__ w2t,    // [4][128][128]
    const bf16t* __restrict__ w3t,    // [128][128]
    const float* __restrict__ w1last, // [4][128]
    float* __restrict__ out)          // [N,128] f32
{
  __shared__ __align__(16) bf16t hbuf[32 * HH];  // 8 KB wave-private h slab

  const int lane = threadIdx.x;       // 0..63 (one wave)
  const int q    = lane >> 4;
  const int l15  = lane & 15;
  const int rowbase = blockIdx.x * 32;

  const f4v fzero = {0.0f, 0.0f, 0.0f, 0.0f};

  f4v emb[2][8];
  #pragma unroll
  for (int rt = 0; rt < 2; ++rt)
    #pragma unroll
    for (int nt = 0; nt < 8; ++nt) emb[rt][nt] = fzero;

  for (int d = 0; d < DD; ++d) {
    // ---- per-lane freqs: k' = j2*32 + q*8 + j ----
    f4v f0 = *(const f4v*)(freqs + d * FF + q * 8);
    f4v f1 = *(const f4v*)(freqs + d * FF + q * 8 + 4);
    f4v f2 = *(const f4v*)(freqs + d * FF + 32 + q * 8);
    f4v f3 = *(const f4v*)(freqs + d * FF + 32 + q * 8 + 4);

    // ---- A-fragments in-register via HW trig (revolutions) ----
    // af[rt][kk]: A[m = rt*16 + l15][k = kk*32 + q*8 + j]
    // k<64 -> cos(c*f[k]); k>=64 -> sin(c*f[k-64])
    bf8v af[2][4];
    #pragma unroll
    for (int rt = 0; rt < 2; ++rt) {
      float cc = cont[(rowbase + rt * 16 + l15) * DD + d];
      #pragma unroll
      for (int j = 0; j < 4; ++j) {
        float t;
        t = cc * f0[j]; t -= floorf(t);
        af[rt][0][j]     = (bf16t)__builtin_amdgcn_cosf(t);
        af[rt][2][j]     = (bf16t)__builtin_amdgcn_sinf(t);
        t = cc * f1[j]; t -= floorf(t);
        af[rt][0][4 + j] = (bf16t)__builtin_amdgcn_cosf(t);
        af[rt][2][4 + j] = (bf16t)__builtin_amdgcn_sinf(t);
        t = cc * f2[j]; t -= floorf(t);
        af[rt][1][j]     = (bf16t)__builtin_amdgcn_cosf(t);
        af[rt][3][j]     = (bf16t)__builtin_amdgcn_sinf(t);
        t = cc * f3[j]; t -= floorf(t);
        af[rt][1][4 + j] = (bf16t)__builtin_amdgcn_cosf(t);
        af[rt][3][4 + j] = (bf16t)__builtin_amdgcn_sinf(t);
      }
    }

    // ---- GEMM1: acc = feat @ w1[:128,:], B-frags streamed from global (L2) ----
    f4v acc[2][8];
    #pragma unroll
    for (int rt = 0; rt < 2; ++rt)
      #pragma unroll
      for (int nt = 0; nt < 8; ++nt) acc[rt][nt] = fzero;

    const bf16t* w1d = w1t + d * HH * HH;
    #pragma unroll
    for (int kk = 0; kk < 4; ++kk) {
      #pragma unroll
      for (int nt = 0; nt < 8; ++nt) {
        bf8v b = *(const bf8v*)&w1d[(nt * 16 + l15) * HH + kk * 32 + q * 8];
        acc[0][nt] = __builtin_amdgcn_mfma_f32_16x16x32_bf16(af[0][kk], b, acc[0][nt], 0, 0, 0);
        acc[1][nt] = __builtin_amdgcn_mfma_f32_16x16x32_bf16(af[1][kk], b, acc[1][nt], 0, 0, 0);
      }
    }

    // ---- epilogue: + b1 + rank-1 (f32 exact), LayerNorm, ReLU -> hbuf (bf16) ----
    float w1l[8], b1v[8], gv[8], bv[8];
    #pragma unroll
    for (int nt = 0; nt < 8; ++nt) {
      int n = nt * 16 + l15;
      w1l[nt] = w1last[d * HH + n];
      b1v[nt] = b1[d * HH + n];
      gv[nt]  = ln1g[d * HH + n];
      bv[nt]  = ln1b[d * HH + n];
    }
    #pragma unroll
    for (int rt = 0; rt < 2; ++rt) {
      float cv[4], s[4], ss[4];
      #pragma unroll
      for (int r = 0; r < 4; ++r) {
        cv[r] = cont[(rowbase + rt * 16 + q * 4 + r) * DD + d];
        s[r] = 0.0f; ss[r] = 0.0f;
      }
      #pragma unroll
      for (int nt = 0; nt < 8; ++nt)
        #pragma unroll
        for (int r = 0; r < 4; ++r) {
          float v = acc[rt][nt][r] + b1v[nt] + cv[r] * w1l[nt];
          acc[rt][nt][r] = v;
          s[r] += v; ss[r] += v * v;
        }
      #pragma unroll
      for (int m = 1; m < 16; m <<= 1)
        #pragma unroll
        for (int r = 0; r < 4; ++r) {
          s[r]  += __shfl_xor(s[r],  m);
          ss[r] += __shfl_xor(ss[r], m);
        }
      #pragma unroll
      for (int r = 0; r < 4; ++r) {
        float mu   = s[r] * (1.0f / 128.0f);
        float var  = ss[r] * (1.0f / 128.0f) - mu * mu;
        float rstd = rsqrtf(var + 1e-5f);
        int mrow = rt * 16 + q * 4 + r;   // local row 0..31
        #pragma unroll
        for (int nt = 0; nt < 8; ++nt) {
          float v = (acc[rt][nt][r] - mu) * rstd * gv[nt] + bv[nt];
          v = fmaxf(v, 0.0f);
          hbuf[swz(mrow, nt * 16 + l15)] = (bf16t)v;
        }
      }
    }
    // same-wave LDS RAW: compiler inserts lgkmcnt wait; no barrier needed

    // ---- GEMM2: emb += h_relu @ w2, A from LDS, B from global ----
    const bf16t* w2d = w2t + d * HH * HH;
    #pragma unroll
    for (int kk = 0; kk < 4; ++kk) {
      bf8v a0 = *(const bf8v*)&hbuf[swz(l15,      kk * 32 + q * 8)];
      bf8v a1 = *(const bf8v*)&hbuf[swz(16 + l15, kk * 32 + q * 8)];
      #pragma unroll
      for (int nt = 0; nt < 8; ++nt) {
        bf8v b = *(const bf8v*)&w2d[(nt * 16 + l15) * HH + kk * 32 + q * 8];
        emb[0][nt] = __builtin_amdgcn_mfma_f32_16x16x32_bf16(a0, b, emb[0][nt], 0, 0, 0);
        emb[1][nt] = __builtin_amdgcn_mfma_f32_16x16x32_bf16(a1, b, emb[1][nt], 0, 0, 0);
      }
    }
    // + b2[d]
    #pragma unroll
    for (int nt = 0; nt < 8; ++nt) {
      float b2v = b2[d * HH + nt * 16 + l15];
      #pragma unroll
      for (int rt = 0; rt < 2; ++rt)
        #pragma unroll
        for (int r = 0; r < 4; ++r) emb[rt][nt][r] += b2v;
    }
  } // d loop

  // ---- final LayerNorm + ReLU on emb -> hbuf (bf16) ----
  {
    float gv[8], bv[8];
    #pragma unroll
    for (int nt = 0; nt < 8; ++nt) {
      gv[nt] = outg[nt * 16 + l15];
      bv[nt] = outb[nt * 16 + l15];
    }
    #pragma unroll
    for (int rt = 0; rt < 2; ++rt) {
      float s[4], ss[4];
      #pragma unroll
      for (int r = 0; r < 4; ++r) { s[r] = 0.0f; ss[r] = 0.0f; }
      #pragma unroll
      for (int nt = 0; nt < 8; ++nt)
        #pragma unroll
        for (int r = 0; r < 4; ++r) {
          float v = emb[rt][nt][r];
          s[r] += v; ss[r] += v * v;
        }
      #pragma unroll
      for (int m = 1; m < 16; m <<= 1)
        #pragma unroll
        for (int r = 0; r < 4; ++r) {
          s[r]  += __shfl_xor(s[r],  m);
          ss[r] += __shfl_xor(ss[r], m);
        }
      #pragma unroll
      for (int r = 0; r < 4; ++r) {
        float mu   = s[r] * (1.0f / 128.0f);
        float var  = ss[r] * (1.0f / 128.0f) - mu * mu;
        float rstd = rsqrtf(var + 1e-5f);
        int mrow = rt * 16 + q * 4 + r;
        #pragma unroll
        for (int nt = 0; nt < 8; ++nt) {
          float v = (emb[rt][nt][r] - mu) * rstd * gv[nt] + bv[nt];
          v = fmaxf(v, 0.0f);
          hbuf[swz(mrow, nt * 16 + l15)] = (bf16t)v;
        }
      }
    }
  }

  // ---- GEMM3: out = ln_relu(emb) @ w3 + b3 ----
  f4v acc[2][8];
  #pragma unroll
  for (int rt = 0; rt < 2; ++rt)
    #pragma unroll
    for (int nt = 0; nt < 8; ++nt) acc[rt][nt] = fzero;

  #pragma unroll
  for (int kk = 0; kk < 4; ++kk) {
    bf8v a0 = *(const bf8v*)&hbuf[swz(l15,      kk * 32 + q * 8)];
    bf8v a1 = *(const bf8v*)&hbuf[swz(16 + l15, kk * 32 + q * 8)];
    #pragma unroll
    for (int nt = 0; nt < 8; ++nt) {
      bf8v b = *(const bf8v*)&w3t[(nt * 16 + l15) * HH + kk * 32 + q * 8];
      acc[0][nt] = __builtin_amdgcn_mfma_f32_16x16x32_bf16(a0, b, acc[0][nt], 0, 0, 0);
      acc[1][nt] = __builtin_amdgcn_mfma_f32_16x16x32_bf16(a1, b, acc[1][nt], 0, 0, 0);
    }
  }
  #pragma unroll
  for (int nt = 0; nt < 8; ++nt) {
    float b3v = b3[nt * 16 + l15];
    #pragma unroll
    for (int rt = 0; rt < 2; ++rt)
      #pragma unroll
      for (int r = 0; r < 4; ++r)
        out[(rowbase + rt * 16 + q * 4 + r) * HH + nt * 16 + l15] =
            acc[rt][nt][r] + b3v;
  }
}

extern "C" void kernel_launch(void* const* d_in, const int* in_sizes, int n_in,
                              void* d_out, int out_size, void* d_ws, size_t ws_size,
                              hipStream_t stream) {
  const float* cont  = (const float*)d_in[0];
  const float* freqs = (const float*)d_in[1];
  const float* w1    = (const float*)d_in[2];
  const float* b1    = (const float*)d_in[3];
  const float* ln1g  = (const float*)d_in[4];
  const float* ln1b  = (const float*)d_in[5];
  const float* w2    = (const float*)d_in[6];
  const float* b2    = (const float*)d_in[7];
  const float* outg  = (const float*)d_in[8];
  const float* outb  = (const float*)d_in[9];
  const float* w3    = (const float*)d_in[10];
  const float* b3    = (const float*)d_in[11];
  float* out = (float*)d_out;

  // ws layout: w1t[65536] bf16 | w2t[65536] bf16 | w3t[16384] bf16 | w1last[512] f32
  bf16t* w1t = (bf16t*)d_ws;
  bf16t* w2t = w1t + DD * HH * HH;
  bf16t* w3t = w2t + DD * HH * HH;
  float* w1last = (float*)((char*)d_ws + (2 * DD * HH * HH + HH * HH) * sizeof(bf16t));

  prep_weights<<<9, 256, 0, stream>>>(w1, w2, w3, w1t, w2t, w3t, w1last);

  int n_rows = in_sizes[0] / DD;       // 131072
  int grid = n_rows / 32;              // 4096 one-wave blocks
  fourier_mlp<<<grid, 64, 0, stream>>>(
      cont, freqs, b1, ln1g, ln1b, b2, outg, outb, b3,
      w1t, w2t, w3t, w1last, out);
}